// Round 4
// baseline (448.396 us; speedup 1.0000x reference)
//
#include <hip/hip_runtime.h>
#include <hip/hip_bf16.h>

// Problem constants
#define B_ 16
#define C_ 512
#define H_ 28
#define W_ 28
#define TPREV 15
#define TT 16          // TPREV + 1
#define HEADS_ 16
#define DHEAD 32       // C_/HEADS_
#define HW 784         // H_*W_
#define HW4 196        // HW/4
#define HW8 98         // HW/8
#define NORM 0.17677669529663687f  // 1/sqrt(32)

typedef float f32x4 __attribute__((ext_vector_type(4)));  // native vector for nontemporal builtins

// ---------------- Kernel 1: global average pool  y[b,c] = mean_hw x ----------------
__global__ __launch_bounds__(64) void pool_kernel(const float* __restrict__ x,
                                                  float* __restrict__ y) {
    const int bc = blockIdx.x;                    // 0..B*C-1
    const f32x4* __restrict__ xr = (const f32x4*)(x + (size_t)bc * HW);
    const int lane = threadIdx.x;                 // 64 lanes
    float s = 0.0f;
    for (int i = lane; i < HW4; i += 64) {
        f32x4 v = xr[i];
        s += v.x + v.y + v.z + v.w;
    }
    #pragma unroll
    for (int off = 32; off > 0; off >>= 1) s += __shfl_down(s, off);
    if (lane == 0) y[bc] = s * (1.0f / (float)HW);
}

// ---------------- Kernel 2: ECA conv1d Q/k, K concat, attention softmax ----------------
__global__ __launch_bounds__(256) void attn_kernel(const float* __restrict__ y,
                                                   const float* __restrict__ prevK,
                                                   const float* __restrict__ wq,
                                                   const float* __restrict__ wk,
                                                   float* __restrict__ Kout,
                                                   float* __restrict__ att) {
    const int b = blockIdx.x;
    const int tid = threadIdx.x;
    __shared__ float y_s[C_];
    __shared__ float Q_s[C_];
    __shared__ float K_s[TT * 513];       // padded stride to avoid bank conflicts
    __shared__ float logit[HEADS_][17];

    // load y row
    y_s[tid]       = y[b * C_ + tid];
    y_s[tid + 256] = y[b * C_ + tid + 256];

    const float q0 = wq[0], q1 = wq[1], q2 = wq[2], q3 = wq[3], q4 = wq[4];
    const float k0 = wk[0], k1 = wk[1], k2 = wk[2], k3 = wk[3], k4 = wk[4];

    // stage prev_K into LDS
    for (int i = tid; i < TPREV * C_; i += 256) {
        int t = i >> 9, c = i & (C_ - 1);
        K_s[t * 513 + c] = prevK[((size_t)b * TPREV + t) * C_ + c];
    }
    __syncthreads();

    // conv1d over channels (SAME, zero pad), cross-correlation
    for (int c = tid; c < C_; c += 256) {
        float a0 = (c >= 2)      ? y_s[c - 2] : 0.0f;
        float a1 = (c >= 1)      ? y_s[c - 1] : 0.0f;
        float a2 = y_s[c];
        float a3 = (c <= C_ - 2) ? y_s[c + 1] : 0.0f;
        float a4 = (c <= C_ - 3) ? y_s[c + 2] : 0.0f;
        Q_s[c]               = a0 * q0 + a1 * q1 + a2 * q2 + a3 * q3 + a4 * q4;
        K_s[TPREV * 513 + c] = a0 * k0 + a1 * k1 + a2 * k2 + a3 * k3 + a4 * k4;
    }
    __syncthreads();

    // write K output (concat prev_K, k)
    for (int i = tid; i < TT * C_; i += 256) {
        int t = i >> 9, c = i & (C_ - 1);
        Kout[((size_t)b * TT + t) * C_ + c] = K_s[t * 513 + c];
    }

    // logits: thread (g,t)
    const int g = tid >> 4, t = tid & 15;
    float s = 0.0f;
    #pragma unroll
    for (int d = 0; d < DHEAD; ++d)
        s += Q_s[g * DHEAD + d] * K_s[t * 513 + g * DHEAD + d];
    s *= NORM;
    logit[g][t] = s;
    __syncthreads();

    float m = -1e30f;
    #pragma unroll
    for (int j = 0; j < TT; ++j) m = fmaxf(m, logit[g][j]);
    float sum = 0.0f;
    #pragma unroll
    for (int j = 0; j < TT; ++j) sum += __expf(logit[g][j] - m);
    att[((size_t)b * HEADS_ + g) * TT + t] = __expf(s - m) / sum;
}

// ---------------- Kernel 3: fused depthwise conv + V concat + attention PV ----------------
// One thread per 8 pixels (two f32x4 quads) of one (b,c) channel.
__global__ __launch_bounds__(256) void fuse_kernel(const float* __restrict__ x,
                                                   const float* __restrict__ prevV,
                                                   const float* __restrict__ wv,
                                                   const float* __restrict__ att,
                                                   float* __restrict__ out,
                                                   float* __restrict__ Vout) {
    const int i = blockIdx.x * 256 + threadIdx.x;   // 0 .. B*C*HW8-1
    const int p8 = i % HW8;
    const int bc = i / HW8;
    const int c  = bc & (C_ - 1);
    const int b  = bc >> 9;
    const int g  = c >> 5;

    float wv9[9];
    #pragma unroll
    for (int k = 0; k < 9; ++k) wv9[k] = wv[c * 9 + k];
    const float* __restrict__ xbc = x + (size_t)bc * HW;

    // ---- depthwise 3x3 conv (SAME, zero pad) for 2 quads of 4 pixels ----
    f32x4 vq[2];
    #pragma unroll
    for (int q = 0; q < 2; ++q) {
        const int p  = p8 * 8 + q * 4;
        const int h  = p / W_;
        const int w0 = p % W_;        // multiple of 4, quad stays within a row
        float r[3][6];
        #pragma unroll
        for (int ry = 0; ry < 3; ++ry) {
            const int hh = h - 1 + ry;
            if (hh < 0 || hh >= H_) {
                #pragma unroll
                for (int j = 0; j < 6; ++j) r[ry][j] = 0.0f;
            } else {
                const float* row = xbc + hh * W_;
                f32x4 mid = *(const f32x4*)(row + w0);
                r[ry][1] = mid.x; r[ry][2] = mid.y; r[ry][3] = mid.z; r[ry][4] = mid.w;
                r[ry][0] = (w0 > 0)      ? row[w0 - 1] : 0.0f;
                r[ry][5] = (w0 + 4 < W_) ? row[w0 + 4] : 0.0f;
            }
        }
        #pragma unroll
        for (int j = 0; j < 4; ++j) {
            float s = 0.0f;
            #pragma unroll
            for (int ky = 0; ky < 3; ++ky)
                #pragma unroll
                for (int kx = 0; kx < 3; ++kx)
                    s = fmaf(r[ky][j + kx], wv9[ky * 3 + kx], s);
            vq[q][j] = s;
        }
    }

    // ---- attention row ----
    const float* __restrict__ arow = att + ((size_t)b * HEADS_ + g) * TT;

    f32x4* __restrict__ Vo = (f32x4*)Vout;
    const f32x4* __restrict__ Pv = (const f32x4*)prevV;
    const int p4 = p8 * 2;

    // t = 15 (new v): streaming stores, no reuse -> nontemporal
    f32x4 acc0, acc1;
    {
        const float a = arow[TPREV];
        const size_t base = (((size_t)b * TT + TPREV) * C_ + c) * HW4 + p4;
        __builtin_nontemporal_store(vq[0], &Vo[base]);
        __builtin_nontemporal_store(vq[1], &Vo[base + 1]);
        acc0 = vq[0] * a;
        acc1 = vq[1] * a;
    }

    #pragma unroll
    for (int t = 0; t < TPREV; ++t) {
        const size_t rbase = (((size_t)b * TPREV + t) * C_ + c) * HW4 + p4;
        const size_t wbase = (((size_t)b * TT    + t) * C_ + c) * HW4 + p4;
        f32x4 pv0 = __builtin_nontemporal_load(&Pv[rbase]);
        f32x4 pv1 = __builtin_nontemporal_load(&Pv[rbase + 1]);
        __builtin_nontemporal_store(pv0, &Vo[wbase]);
        __builtin_nontemporal_store(pv1, &Vo[wbase + 1]);
        const float a = arow[t];
        acc0.x = fmaf(a, pv0.x, acc0.x);
        acc0.y = fmaf(a, pv0.y, acc0.y);
        acc0.z = fmaf(a, pv0.z, acc0.z);
        acc0.w = fmaf(a, pv0.w, acc0.w);
        acc1.x = fmaf(a, pv1.x, acc1.x);
        acc1.y = fmaf(a, pv1.y, acc1.y);
        acc1.z = fmaf(a, pv1.z, acc1.z);
        acc1.w = fmaf(a, pv1.w, acc1.w);
    }
    f32x4* __restrict__ Or = (f32x4*)out;
    __builtin_nontemporal_store(acc0, &Or[(size_t)bc * HW4 + p4]);
    __builtin_nontemporal_store(acc1, &Or[(size_t)bc * HW4 + p4 + 1]);
}

extern "C" void kernel_launch(void* const* d_in, const int* in_sizes, int n_in,
                              void* d_out, int out_size, void* d_ws, size_t ws_size,
                              hipStream_t stream) {
    const float* x     = (const float*)d_in[0];
    const float* prevK = (const float*)d_in[1];
    const float* prevV = (const float*)d_in[2];
    const float* wq    = (const float*)d_in[3];
    const float* wk    = (const float*)d_in[4];
    const float* wv    = (const float*)d_in[5];

    float* out  = (float*)d_out;                       // [B,C,H,W]
    float* Kout = out + (size_t)B_ * C_ * HW;          // [B,TT,C]
    float* Vout = Kout + (size_t)B_ * TT * C_;         // [B,TT,C,H,W]

    float* y_ws   = (float*)d_ws;                      // B*C
    float* att_ws = y_ws + B_ * C_;                    // B*HEADS*TT

    pool_kernel<<<B_ * C_, 64, 0, stream>>>(x, y_ws);
    attn_kernel<<<B_, 256, 0, stream>>>(y_ws, prevK, wq, wk, Kout, att_ws);

    const int total8 = B_ * C_ * HW8;                  // 802,816
    fuse_kernel<<<total8 / 256, 256, 0, stream>>>(x, prevV, wv, att_ws, out, Vout);
}

// Round 5
// 162.659 us; speedup vs baseline: 2.7567x; 2.7567x over previous
//
#include <hip/hip_runtime.h>
#include <hip/hip_bf16.h>

// Problem constants
#define B_ 16
#define C_ 512
#define H_ 28
#define W_ 28
#define TPREV 15
#define TT 16          // TPREV + 1
#define HEADS_ 16
#define DHEAD 32       // C_/HEADS_
#define HW 784         // H_*W_
#define HW4 196        // HW/4
#define CH4 (C_ * HW4) // quads per (b,t) slab = 100352
#define NORM 0.17677669529663687f  // 1/sqrt(32)

typedef float f32x4 __attribute__((ext_vector_type(4)));  // native vector for nontemporal builtins

// ---------------- Kernel 1: global average pool  y[b,c] = mean_hw x ----------------
__global__ __launch_bounds__(64) void pool_kernel(const float* __restrict__ x,
                                                  float* __restrict__ y) {
    const int bc = blockIdx.x;                    // 0..B*C-1
    const f32x4* __restrict__ xr = (const f32x4*)(x + (size_t)bc * HW);
    const int lane = threadIdx.x;                 // 64 lanes
    float s = 0.0f;
    for (int i = lane; i < HW4; i += 64) {
        f32x4 v = xr[i];
        s += v.x + v.y + v.z + v.w;
    }
    #pragma unroll
    for (int off = 32; off > 0; off >>= 1) s += __shfl_down(s, off);
    if (lane == 0) y[bc] = s * (1.0f / (float)HW);
}

// ---------------- Kernel 2: ECA conv1d Q/k, K concat, attention softmax ----------------
__global__ __launch_bounds__(256) void attn_kernel(const float* __restrict__ y,
                                                   const float* __restrict__ prevK,
                                                   const float* __restrict__ wq,
                                                   const float* __restrict__ wk,
                                                   float* __restrict__ Kout,
                                                   float* __restrict__ att) {
    const int b = blockIdx.x;
    const int tid = threadIdx.x;
    __shared__ float y_s[C_];
    __shared__ float Q_s[C_];
    __shared__ float K_s[TT * 513];       // padded stride to avoid bank conflicts
    __shared__ float logit[HEADS_][17];

    // load y row
    y_s[tid]       = y[b * C_ + tid];
    y_s[tid + 256] = y[b * C_ + tid + 256];

    const float q0 = wq[0], q1 = wq[1], q2 = wq[2], q3 = wq[3], q4 = wq[4];
    const float k0 = wk[0], k1 = wk[1], k2 = wk[2], k3 = wk[3], k4 = wk[4];

    // stage prev_K into LDS
    for (int i = tid; i < TPREV * C_; i += 256) {
        int t = i >> 9, c = i & (C_ - 1);
        K_s[t * 513 + c] = prevK[((size_t)b * TPREV + t) * C_ + c];
    }
    __syncthreads();

    // conv1d over channels (SAME, zero pad), cross-correlation
    for (int c = tid; c < C_; c += 256) {
        float a0 = (c >= 2)      ? y_s[c - 2] : 0.0f;
        float a1 = (c >= 1)      ? y_s[c - 1] : 0.0f;
        float a2 = y_s[c];
        float a3 = (c <= C_ - 2) ? y_s[c + 1] : 0.0f;
        float a4 = (c <= C_ - 3) ? y_s[c + 2] : 0.0f;
        Q_s[c]               = a0 * q0 + a1 * q1 + a2 * q2 + a3 * q3 + a4 * q4;
        K_s[TPREV * 513 + c] = a0 * k0 + a1 * k1 + a2 * k2 + a3 * k3 + a4 * k4;
    }
    __syncthreads();

    // write K output (concat prev_K, k)
    for (int i = tid; i < TT * C_; i += 256) {
        int t = i >> 9, c = i & (C_ - 1);
        Kout[((size_t)b * TT + t) * C_ + c] = K_s[t * 513 + c];
    }

    // logits: thread (g,t)
    const int g = tid >> 4, t = tid & 15;
    float s = 0.0f;
    #pragma unroll
    for (int d = 0; d < DHEAD; ++d)
        s += Q_s[g * DHEAD + d] * K_s[t * 513 + g * DHEAD + d];
    s *= NORM;
    logit[g][t] = s;
    __syncthreads();

    float m = -1e30f;
    #pragma unroll
    for (int j = 0; j < TT; ++j) m = fmaxf(m, logit[g][j]);
    float sum = 0.0f;
    #pragma unroll
    for (int j = 0; j < TT; ++j) sum += __expf(logit[g][j] - m);
    att[((size_t)b * HEADS_ + g) * TT + t] = __expf(s - m) / sum;
}

// ---------------- Kernel 3: fused depthwise conv + V concat + attention PV ----------------
// Each thread owns TWO flat quads, 64 lanes apart: every load/store instruction
// stays unit-stride across the wave (2 contiguous 1KB segments per instr pair).
__global__ __launch_bounds__(256) void fuse_kernel(const float* __restrict__ x,
                                                   const float* __restrict__ prevV,
                                                   const float* __restrict__ wv,
                                                   const float* __restrict__ att,
                                                   float* __restrict__ out,
                                                   float* __restrict__ Vout) {
    const int tid  = threadIdx.x;
    const int lane = tid & 63;
    const int wave = tid >> 6;
    const int q0   = blockIdx.x * 512 + wave * 128 + lane;  // flat quad index (quad = f32x4)

    f32x4 vnew[2];
    const float* arow[2];
    size_t pvq[2];   // flat quad offset into prevV at t=0
    size_t voq[2];   // flat quad offset into Vout at t=0
    size_t outq[2];  // flat quad offset into out

    #pragma unroll
    for (int j = 0; j < 2; ++j) {
        const int idx = q0 + j * 64;
        const int p4  = idx % HW4;
        const int bc  = idx / HW4;
        const int c   = bc & (C_ - 1);
        const int b   = bc >> 9;
        const int g   = c >> 5;

        // ---- depthwise 3x3 conv (SAME, zero pad) for this quad ----
        const float* __restrict__ xbc = x + (size_t)bc * HW;
        const int p  = p4 * 4;
        const int h  = p / W_;
        const int w0 = p % W_;        // multiple of 4, quad stays within a row
        float r[3][6];
        #pragma unroll
        for (int ry = 0; ry < 3; ++ry) {
            const int hh = h - 1 + ry;
            if (hh < 0 || hh >= H_) {
                #pragma unroll
                for (int jj = 0; jj < 6; ++jj) r[ry][jj] = 0.0f;
            } else {
                const float* row = xbc + hh * W_;
                f32x4 mid = *(const f32x4*)(row + w0);
                r[ry][1] = mid.x; r[ry][2] = mid.y; r[ry][3] = mid.z; r[ry][4] = mid.w;
                r[ry][0] = (w0 > 0)      ? row[w0 - 1] : 0.0f;
                r[ry][5] = (w0 + 4 < W_) ? row[w0 + 4] : 0.0f;
            }
        }
        float wv9[9];
        #pragma unroll
        for (int k = 0; k < 9; ++k) wv9[k] = wv[c * 9 + k];
        #pragma unroll
        for (int jj = 0; jj < 4; ++jj) {
            float s = 0.0f;
            #pragma unroll
            for (int ky = 0; ky < 3; ++ky)
                #pragma unroll
                for (int kx = 0; kx < 3; ++kx)
                    s = fmaf(r[ky][jj + kx], wv9[ky * 3 + kx], s);
            vnew[j][jj] = s;
        }

        arow[j] = att + ((size_t)b * HEADS_ + g) * TT;
        pvq[j]  = ((size_t)b * TPREV * C_ + c) * HW4 + p4;
        voq[j]  = ((size_t)b * TT    * C_ + c) * HW4 + p4;
        outq[j] = (size_t)bc * HW4 + p4;
    }

    f32x4* __restrict__ Vo = (f32x4*)Vout;
    const f32x4* __restrict__ Pv = (const f32x4*)prevV;
    f32x4* __restrict__ Or = (f32x4*)out;

    // t = 15 (new v): streaming stores + init accumulators
    f32x4 acc[2];
    #pragma unroll
    for (int j = 0; j < 2; ++j) {
        const float a = arow[j][TPREV];
        __builtin_nontemporal_store(vnew[j], &Vo[voq[j] + (size_t)TPREV * CH4]);
        acc[j] = vnew[j] * a;
    }

    #pragma unroll
    for (int t = 0; t < TPREV; ++t) {
        #pragma unroll
        for (int j = 0; j < 2; ++j) {
            f32x4 pv = __builtin_nontemporal_load(&Pv[pvq[j] + (size_t)t * CH4]);
            __builtin_nontemporal_store(pv, &Vo[voq[j] + (size_t)t * CH4]);
            const float a = arow[j][t];
            acc[j].x = fmaf(a, pv.x, acc[j].x);
            acc[j].y = fmaf(a, pv.y, acc[j].y);
            acc[j].z = fmaf(a, pv.z, acc[j].z);
            acc[j].w = fmaf(a, pv.w, acc[j].w);
        }
    }
    #pragma unroll
    for (int j = 0; j < 2; ++j)
        __builtin_nontemporal_store(acc[j], &Or[outq[j]]);
}

extern "C" void kernel_launch(void* const* d_in, const int* in_sizes, int n_in,
                              void* d_out, int out_size, void* d_ws, size_t ws_size,
                              hipStream_t stream) {
    const float* x     = (const float*)d_in[0];
    const float* prevK = (const float*)d_in[1];
    const float* prevV = (const float*)d_in[2];
    const float* wq    = (const float*)d_in[3];
    const float* wk    = (const float*)d_in[4];
    const float* wv    = (const float*)d_in[5];

    float* out  = (float*)d_out;                       // [B,C,H,W]
    float* Kout = out + (size_t)B_ * C_ * HW;          // [B,TT,C]
    float* Vout = Kout + (size_t)B_ * TT * C_;         // [B,TT,C,H,W]

    float* y_ws   = (float*)d_ws;                      // B*C
    float* att_ws = y_ws + B_ * C_;                    // B*HEADS*TT

    pool_kernel<<<B_ * C_, 64, 0, stream>>>(x, y_ws);
    attn_kernel<<<B_, 256, 0, stream>>>(y_ws, prevK, wq, wk, Kout, att_ws);

    const int totalq = B_ * C_ * HW4;                  // 1,605,632 quads
    fuse_kernel<<<totalq / 512, 256, 0, stream>>>(x, prevV, wv, att_ws, out, Vout);
}

// Round 6
// 160.989 us; speedup vs baseline: 2.7853x; 1.0104x over previous
//
#include <hip/hip_runtime.h>
#include <hip/hip_bf16.h>

// Problem constants
#define B_ 16
#define C_ 512
#define H_ 28
#define W_ 28
#define TPREV 15
#define TT 16          // TPREV + 1
#define HEADS_ 16
#define DHEAD 32       // C_/HEADS_
#define HW 784         // H_*W_
#define HW4 196        // HW/4
#define CH4 (C_ * HW4) // quads per (b,t) slab = 100352
#define NORM 0.17677669529663687f  // 1/sqrt(32)

typedef float f32x4 __attribute__((ext_vector_type(4)));  // native vector for nontemporal builtins

// ---------------- Kernel 1: global average pool  y[b,c] = mean_hw x ----------------
__global__ __launch_bounds__(64) void pool_kernel(const float* __restrict__ x,
                                                  float* __restrict__ y) {
    const int bc = blockIdx.x;                    // 0..B*C-1
    const f32x4* __restrict__ xr = (const f32x4*)(x + (size_t)bc * HW);
    const int lane = threadIdx.x;                 // 64 lanes
    float s = 0.0f;
    for (int i = lane; i < HW4; i += 64) {
        f32x4 v = xr[i];
        s += v.x + v.y + v.z + v.w;
    }
    #pragma unroll
    for (int off = 32; off > 0; off >>= 1) s += __shfl_down(s, off);
    if (lane == 0) y[bc] = s * (1.0f / (float)HW);
}

// ---------------- Kernel 2: ECA conv1d Q/k, K concat, attention softmax ----------------
__global__ __launch_bounds__(256) void attn_kernel(const float* __restrict__ y,
                                                   const float* __restrict__ prevK,
                                                   const float* __restrict__ wq,
                                                   const float* __restrict__ wk,
                                                   float* __restrict__ Kout,
                                                   float* __restrict__ att) {
    const int b = blockIdx.x;
    const int tid = threadIdx.x;
    __shared__ float y_s[C_];
    __shared__ float Q_s[C_];
    __shared__ float K_s[TT * 513];       // padded stride to avoid bank conflicts
    __shared__ float logit[HEADS_][17];

    // load y row
    y_s[tid]       = y[b * C_ + tid];
    y_s[tid + 256] = y[b * C_ + tid + 256];

    const float q0 = wq[0], q1 = wq[1], q2 = wq[2], q3 = wq[3], q4 = wq[4];
    const float k0 = wk[0], k1 = wk[1], k2 = wk[2], k3 = wk[3], k4 = wk[4];

    // stage prev_K into LDS
    for (int i = tid; i < TPREV * C_; i += 256) {
        int t = i >> 9, c = i & (C_ - 1);
        K_s[t * 513 + c] = prevK[((size_t)b * TPREV + t) * C_ + c];
    }
    __syncthreads();

    // conv1d over channels (SAME, zero pad), cross-correlation
    for (int c = tid; c < C_; c += 256) {
        float a0 = (c >= 2)      ? y_s[c - 2] : 0.0f;
        float a1 = (c >= 1)      ? y_s[c - 1] : 0.0f;
        float a2 = y_s[c];
        float a3 = (c <= C_ - 2) ? y_s[c + 1] : 0.0f;
        float a4 = (c <= C_ - 3) ? y_s[c + 2] : 0.0f;
        Q_s[c]               = a0 * q0 + a1 * q1 + a2 * q2 + a3 * q3 + a4 * q4;
        K_s[TPREV * 513 + c] = a0 * k0 + a1 * k1 + a2 * k2 + a3 * k3 + a4 * k4;
    }
    __syncthreads();

    // write K output (concat prev_K, k)
    for (int i = tid; i < TT * C_; i += 256) {
        int t = i >> 9, c = i & (C_ - 1);
        Kout[((size_t)b * TT + t) * C_ + c] = K_s[t * 513 + c];
    }

    // logits: thread (g,t)
    const int g = tid >> 4, t = tid & 15;
    float s = 0.0f;
    #pragma unroll
    for (int d = 0; d < DHEAD; ++d)
        s += Q_s[g * DHEAD + d] * K_s[t * 513 + g * DHEAD + d];
    s *= NORM;
    logit[g][t] = s;
    __syncthreads();

    float m = -1e30f;
    #pragma unroll
    for (int j = 0; j < TT; ++j) m = fmaxf(m, logit[g][j]);
    float sum = 0.0f;
    #pragma unroll
    for (int j = 0; j < TT; ++j) sum += __expf(logit[g][j] - m);
    att[((size_t)b * HEADS_ + g) * TT + t] = __expf(s - m) / sum;
}

// ---------------- Kernel 3: fused depthwise conv + V concat + attention PV ----------------
// One thread per f32x4 quad. Burst-issues all 15 prev_V NT loads into registers
// (240 B/lane in flight = 15 KB/wave) before the store+FMA drain, to cover
// ~375 ns HBM latency at 24.6 B/ns/CU.
__global__ __launch_bounds__(256) void fuse_kernel(const float* __restrict__ x,
                                                   const float* __restrict__ prevV,
                                                   const float* __restrict__ wv,
                                                   const float* __restrict__ att,
                                                   float* __restrict__ out,
                                                   float* __restrict__ Vout) {
    const int i = blockIdx.x * 256 + threadIdx.x;   // 0 .. B*C*HW4-1
    const int p4 = i % HW4;
    const int bc = i / HW4;
    const int c  = bc & (C_ - 1);
    const int b  = bc >> 9;
    const int g  = c >> 5;

    // ---- depthwise 3x3 conv (SAME, zero pad) for 4 consecutive pixels ----
    const float* __restrict__ xbc = x + (size_t)bc * HW;
    const int p  = p4 * 4;
    const int h  = p / W_;
    const int w0 = p % W_;          // multiple of 4 (28 % 4 == 0)
    float r[3][6];
    #pragma unroll
    for (int ry = 0; ry < 3; ++ry) {
        const int hh = h - 1 + ry;
        if (hh < 0 || hh >= H_) {
            #pragma unroll
            for (int j = 0; j < 6; ++j) r[ry][j] = 0.0f;
        } else {
            const float* row = xbc + hh * W_;
            f32x4 mid = *(const f32x4*)(row + w0);
            r[ry][1] = mid.x; r[ry][2] = mid.y; r[ry][3] = mid.z; r[ry][4] = mid.w;
            r[ry][0] = (w0 > 0)      ? row[w0 - 1] : 0.0f;
            r[ry][5] = (w0 + 4 < W_) ? row[w0 + 4] : 0.0f;
        }
    }
    float wv9[9];
    #pragma unroll
    for (int k = 0; k < 9; ++k) wv9[k] = wv[c * 9 + k];

    f32x4 v4;
    #pragma unroll
    for (int j = 0; j < 4; ++j) {
        float s = 0.0f;
        #pragma unroll
        for (int ky = 0; ky < 3; ++ky)
            #pragma unroll
            for (int kx = 0; kx < 3; ++kx)
                s = fmaf(r[ky][j + kx], wv9[ky * 3 + kx], s);
        v4[j] = s;
    }

    const float* __restrict__ arow = att + ((size_t)b * HEADS_ + g) * TT;

    f32x4* __restrict__ Vo = (f32x4*)Vout;
    const f32x4* __restrict__ Pv = (const f32x4*)prevV;
    const size_t pvq = ((size_t)b * TPREV * C_ + c) * HW4 + p4;  // prevV quad @ t=0
    const size_t voq = ((size_t)b * TT    * C_ + c) * HW4 + p4;  // Vout  quad @ t=0

    // ---- burst: issue all 15 prev_V loads ----
    f32x4 pv[TPREV];
    #pragma unroll
    for (int t = 0; t < TPREV; ++t)
        pv[t] = __builtin_nontemporal_load(&Pv[pvq + (size_t)t * CH4]);

    // t = 15 (new v): streaming store + init accumulator
    f32x4 acc;
    {
        const float a = arow[TPREV];
        __builtin_nontemporal_store(v4, &Vo[voq + (size_t)TPREV * CH4]);
        acc = v4 * a;
    }

    // ---- drain: store-through + FMA ----
    #pragma unroll
    for (int t = 0; t < TPREV; ++t) {
        __builtin_nontemporal_store(pv[t], &Vo[voq + (size_t)t * CH4]);
        const float a = arow[t];
        acc.x = fmaf(a, pv[t].x, acc.x);
        acc.y = fmaf(a, pv[t].y, acc.y);
        acc.z = fmaf(a, pv[t].z, acc.z);
        acc.w = fmaf(a, pv[t].w, acc.w);
    }
    __builtin_nontemporal_store(acc, &((f32x4*)out)[(size_t)bc * HW4 + p4]);
}

extern "C" void kernel_launch(void* const* d_in, const int* in_sizes, int n_in,
                              void* d_out, int out_size, void* d_ws, size_t ws_size,
                              hipStream_t stream) {
    const float* x     = (const float*)d_in[0];
    const float* prevK = (const float*)d_in[1];
    const float* prevV = (const float*)d_in[2];
    const float* wq    = (const float*)d_in[3];
    const float* wk    = (const float*)d_in[4];
    const float* wv    = (const float*)d_in[5];

    float* out  = (float*)d_out;                       // [B,C,H,W]
    float* Kout = out + (size_t)B_ * C_ * HW;          // [B,TT,C]
    float* Vout = Kout + (size_t)B_ * TT * C_;         // [B,TT,C,H,W]

    float* y_ws   = (float*)d_ws;                      // B*C
    float* att_ws = y_ws + B_ * C_;                    // B*HEADS*TT

    pool_kernel<<<B_ * C_, 64, 0, stream>>>(x, y_ws);
    attn_kernel<<<B_, 256, 0, stream>>>(y_ws, prevK, wq, wk, Kout, att_ws);

    const int totalq = B_ * C_ * HW4;                  // 1,605,632 quads
    fuse_kernel<<<totalq / 256, 256, 0, stream>>>(x, prevV, wv, att_ws, out, Vout);
}

// Round 8
// 159.517 us; speedup vs baseline: 2.8110x; 1.0092x over previous
//
#include <hip/hip_runtime.h>
#include <hip/hip_bf16.h>

// Problem constants
#define B_ 16
#define C_ 512
#define H_ 28
#define W_ 28
#define TPREV 15
#define TT 16          // TPREV + 1
#define HEADS_ 16
#define DHEAD 32       // C_/HEADS_
#define HW 784         // H_*W_
#define HW4 196        // HW/4
#define CH4 (C_ * HW4) // quads per (b,t) slab = 100352
#define NORM 0.17677669529663687f  // 1/sqrt(32)

typedef float f32x4 __attribute__((ext_vector_type(4)));  // native vector for nontemporal builtins

#define POOL_BLOCKS (B_ * C_)               // 8192 blocks of 64 threads, one per (b,c)
#define KCOPY_QUADS (B_ * TPREV * C_ / 4)   // 30720 f32x4 quads of prev_K
#define KCOPY_BLOCKS (KCOPY_QUADS / 64)     // 480

// ---------------- Kernel 1: global average pool + prev_K -> Kout copy ----------------
__global__ __launch_bounds__(64) void pool_copy_kernel(const float* __restrict__ x,
                                                       const float* __restrict__ prevK,
                                                       float* __restrict__ y,
                                                       float* __restrict__ Kout) {
    const int lane = threadIdx.x;
    if (blockIdx.x < POOL_BLOCKS) {
        const int bc = blockIdx.x;                    // 0..B*C-1
        const f32x4* __restrict__ xr = (const f32x4*)(x + (size_t)bc * HW);
        float s = 0.0f;
        for (int i = lane; i < HW4; i += 64) {
            f32x4 v = xr[i];
            s += v.x + v.y + v.z + v.w;
        }
        #pragma unroll
        for (int off = 32; off > 0; off >>= 1) s += __shfl_down(s, off);
        if (lane == 0) y[bc] = s * (1.0f / (float)HW);
    } else {
        // copy prev_K [B,15,C] into Kout [B,16,C] (t<15 region), quad-wise
        const int j = (blockIdx.x - POOL_BLOCKS) * 64 + lane;   // 0..30719
        const f32x4* __restrict__ src = (const f32x4*)prevK;
        f32x4* __restrict__ dst = (f32x4*)Kout;
        const int b = j / (TPREV * C_ / 4);           // / 1920
        dst[j + b * (C_ / 4)] = src[j];               // skip the t=15 slot per batch
    }
}

// ---------------- Kernel 2: fused att-compute + depthwise conv + V concat + PV ----------------
// A 256-quad block spans up to THREE (b,c) channels (196 quads/channel, 256 > 196).
// Lanes 0..95 (3 half-groups of 32) recompute the att rows for channels bc_lo..bc_lo+2
// from y/prev_K/wq/wk (tiny, cached), plus write Kout[b,15,:] for owned channels.
__global__ __launch_bounds__(256) void fuse_kernel(const float* __restrict__ x,
                                                   const float* __restrict__ prevV,
                                                   const float* __restrict__ prevK,
                                                   const float* __restrict__ y,
                                                   const float* __restrict__ wq,
                                                   const float* __restrict__ wk,
                                                   const float* __restrict__ wv,
                                                   float* __restrict__ out,
                                                   float* __restrict__ Kout,
                                                   float* __restrict__ Vout) {
    const int tid = threadIdx.x;
    const int blk0 = blockIdx.x * 256;                // first flat quad of block
    __shared__ float att_s[3][TT];

    const int bc_lo = blk0 / HW4;
    const int bc_hi = (blk0 + 255) / HW4;             // bc_lo, +1, or +2

    // ---- att phase: lanes 0..95 ----
    if (tid < 96) {
        const int half = tid >> 5;                    // 0..2: which spanned channel
        const int d    = tid & 31;
        const int bcx  = bc_lo + half;
        if (bcx <= bc_hi) {                           // also guards bcx < B_*C_
            const int bb = bcx >> 9;
            const int gg = (bcx & (C_ - 1)) >> 5;
            const int cc = gg * DHEAD + d;

            // conv1d (SAME, zero pad) for Q and k at channel cc
            float Qc = 0.0f, kc = 0.0f;
            #pragma unroll
            for (int j = 0; j < 5; ++j) {
                const int cj = cc - 2 + j;
                const float yv = (cj >= 0 && cj < C_) ? y[bb * C_ + cj] : 0.0f;
                Qc = fmaf(yv, wq[j], Qc);
                kc = fmaf(yv, wk[j], kc);
            }

            // per-lane logit partials over t
            float pl[TT];
            #pragma unroll
            for (int t = 0; t < TPREV; ++t)
                pl[t] = Qc * prevK[((size_t)bb * TPREV + t) * C_ + cc];
            pl[TPREV] = Qc * kc;

            // butterfly reduce across the 32-lane half (xor masks stay within the half)
            #pragma unroll
            for (int m = 1; m <= 16; m <<= 1) {
                #pragma unroll
                for (int t = 0; t < TT; ++t)
                    pl[t] += __shfl_xor(pl[t], m);
            }

            // softmax (every lane has all 16 sums; redundant identical fp32 math)
            float mx = -1e30f;
            #pragma unroll
            for (int t = 0; t < TT; ++t) mx = fmaxf(mx, pl[t] * NORM);
            float sum = 0.0f;
            #pragma unroll
            for (int t = 0; t < TT; ++t) sum += __expf(pl[t] * NORM - mx);
            if (d < TT)
                att_s[half][d] = __expf(pl[d] * NORM - mx) / sum;

            // Kout[b,15,cc]: written by the unique block containing quad (bb*C_+cc)*HW4
            // (duplicate writers across halves carry identical values — benign)
            const int qk = (bb * C_ + cc) * HW4;
            if (qk >= blk0 && qk < blk0 + 256)
                Kout[((size_t)bb * TT + TPREV) * C_ + cc] = kc;
        }
    }
    __syncthreads();

    // ---- streaming phase (identical to proven round-6 pattern) ----
    const int i  = blk0 + tid;                        // flat quad index
    const int p4 = i % HW4;
    const int bc = i / HW4;
    const int c  = bc & (C_ - 1);
    const int b  = bc >> 9;
    const int h_ = bc - bc_lo;                        // 0..2: which att row

    f32x4* __restrict__ Vo = (f32x4*)Vout;
    const f32x4* __restrict__ Pv = (const f32x4*)prevV;
    const size_t pvq = ((size_t)b * TPREV * C_ + c) * HW4 + p4;  // prevV quad @ t=0
    const size_t voq = ((size_t)b * TT    * C_ + c) * HW4 + p4;  // Vout  quad @ t=0

    // burst: issue all 15 prev_V NT loads first (15 KB/wave in flight)
    f32x4 pv[TPREV];
    #pragma unroll
    for (int t = 0; t < TPREV; ++t)
        pv[t] = __builtin_nontemporal_load(&Pv[pvq + (size_t)t * CH4]);

    // depthwise 3x3 conv (SAME, zero pad) for 4 consecutive pixels — overlaps load latency
    const float* __restrict__ xbc = x + (size_t)bc * HW;
    const int p  = p4 * 4;
    const int h  = p / W_;
    const int w0 = p % W_;          // multiple of 4 (28 % 4 == 0)
    float r[3][6];
    #pragma unroll
    for (int ry = 0; ry < 3; ++ry) {
        const int hh = h - 1 + ry;
        if (hh < 0 || hh >= H_) {
            #pragma unroll
            for (int j = 0; j < 6; ++j) r[ry][j] = 0.0f;
        } else {
            const float* row = xbc + hh * W_;
            f32x4 mid = *(const f32x4*)(row + w0);
            r[ry][1] = mid.x; r[ry][2] = mid.y; r[ry][3] = mid.z; r[ry][4] = mid.w;
            r[ry][0] = (w0 > 0)      ? row[w0 - 1] : 0.0f;
            r[ry][5] = (w0 + 4 < W_) ? row[w0 + 4] : 0.0f;
        }
    }
    float wv9[9];
    #pragma unroll
    for (int k = 0; k < 9; ++k) wv9[k] = wv[c * 9 + k];

    f32x4 v4;
    #pragma unroll
    for (int j = 0; j < 4; ++j) {
        float s = 0.0f;
        #pragma unroll
        for (int ky = 0; ky < 3; ++ky)
            #pragma unroll
            for (int kx = 0; kx < 3; ++kx)
                s = fmaf(r[ky][j + kx], wv9[ky * 3 + kx], s);
        v4[j] = s;
    }

    // t = 15 (new v): streaming store + init accumulator
    f32x4 acc;
    {
        const float a = att_s[h_][TPREV];
        __builtin_nontemporal_store(v4, &Vo[voq + (size_t)TPREV * CH4]);
        acc = v4 * a;
    }

    // drain: store-through + FMA
    #pragma unroll
    for (int t = 0; t < TPREV; ++t) {
        __builtin_nontemporal_store(pv[t], &Vo[voq + (size_t)t * CH4]);
        const float a = att_s[h_][t];
        acc.x = fmaf(a, pv[t].x, acc.x);
        acc.y = fmaf(a, pv[t].y, acc.y);
        acc.z = fmaf(a, pv[t].z, acc.z);
        acc.w = fmaf(a, pv[t].w, acc.w);
    }
    __builtin_nontemporal_store(acc, &((f32x4*)out)[(size_t)bc * HW4 + p4]);
}

extern "C" void kernel_launch(void* const* d_in, const int* in_sizes, int n_in,
                              void* d_out, int out_size, void* d_ws, size_t ws_size,
                              hipStream_t stream) {
    const float* x     = (const float*)d_in[0];
    const float* prevK = (const float*)d_in[1];
    const float* prevV = (const float*)d_in[2];
    const float* wq    = (const float*)d_in[3];
    const float* wk    = (const float*)d_in[4];
    const float* wv    = (const float*)d_in[5];

    float* out  = (float*)d_out;                       // [B,C,H,W]
    float* Kout = out + (size_t)B_ * C_ * HW;          // [B,TT,C]
    float* Vout = Kout + (size_t)B_ * TT * C_;         // [B,TT,C,H,W]

    float* y_ws = (float*)d_ws;                        // B*C pooled means

    pool_copy_kernel<<<POOL_BLOCKS + KCOPY_BLOCKS, 64, 0, stream>>>(x, prevK, y_ws, Kout);

    const int totalq = B_ * C_ * HW4;                  // 1,605,632 quads
    fuse_kernel<<<totalq / 256, 256, 0, stream>>>(x, prevV, prevK, y_ws, wq, wk, wv,
                                                  out, Kout, Vout);
}